// Round 5
// baseline (257.538 us; speedup 1.0000x reference)
//
#include <hip/hip_runtime.h>

#define DEV __device__ __forceinline__
#define KSIG (-1.442695041f)
#define KTANH (-2.885390082f)

typedef float f2 __attribute__((ext_vector_type(2)));

DEV float fexp2(float x) { return __builtin_amdgcn_exp2f(x); }
DEV float frcp(float x) { return __builtin_amdgcn_rcpf(x); }
DEV float bperm(int a, float x) {
  return __int_as_float(__builtin_amdgcn_ds_bpermute(a, __float_as_int(x)));
}
DEV f2 pkfma(f2 a, f2 b, f2 c) { return __builtin_elementwise_fma(a, b, c); }

// Lane u of a 5-lane group owns state index j=u and gate rows
// {u, 5+u, 10+u, 15+u} (i,f,g,o). kexp folded into weights/bias:
// sigmoid rows scaled by KSIG, g-row by KTANH; act = rcp(1+exp2(acc)),
// tanh = 2*act-1. Dots use packed f32 FMA (v_pk_fma_f32).
struct CellP {
  f2 wx[4][2];  // x pairs (x0,x1),(x2,x3)
  f2 wh[4][2];  // h pairs (h0,h1),(h2,h3)
  float wx4[4], wh4[4];
  f2 b2[4];  // {bias, 0}
};

DEV void load_cellP(CellP& W, int u, const float* __restrict__ Wih,
                    const float* __restrict__ Whh,
                    const float* __restrict__ bih,
                    const float* __restrict__ bhh) {
#pragma unroll
  for (int rt = 0; rt < 4; ++rt) {  // 0=i 1=f 2=g 3=o
    int row = 5 * rt + u;
    float kx = (rt == 2) ? KTANH : KSIG;
    W.wx[rt][0] = (f2){kx * Wih[row * 5 + 0], kx * Wih[row * 5 + 1]};
    W.wx[rt][1] = (f2){kx * Wih[row * 5 + 2], kx * Wih[row * 5 + 3]};
    W.wx4[rt] = kx * Wih[row * 5 + 4];
    W.wh[rt][0] = (f2){kx * Whh[row * 5 + 0], kx * Whh[row * 5 + 1]};
    W.wh[rt][1] = (f2){kx * Whh[row * 5 + 2], kx * Whh[row * 5 + 3]};
    W.wh4[rt] = kx * Whh[row * 5 + 4];
    W.b2[rt] = (f2){kx * (bih[row] + bhh[row]), 0.f};
  }
}

// One cell timestep. hAll holds h(t-1)[0..4] on entry, h(t)[0..4] on exit.
DEV void stepP(const CellP& W, const f2 xp[2], float x4, float hAll[5],
               float& c, const int bp[5]) {
  f2 hp0 = (f2){hAll[0], hAll[1]};
  f2 hp1 = (f2){hAll[2], hAll[3]};
  float acc[4];
#pragma unroll
  for (int rt = 0; rt < 4; ++rt) {
    f2 a2 = pkfma(W.wx[rt][0], xp[0], W.b2[rt]);
    a2 = pkfma(W.wx[rt][1], xp[1], a2);
    a2 = pkfma(W.wh[rt][0], hp0, a2);
    a2 = pkfma(W.wh[rt][1], hp1, a2);
    float a = a2.x + a2.y;
    a = fmaf(W.wx4[rt], x4, a);
    acc[rt] = fmaf(W.wh4[rt], hAll[4], a);
  }
  float gi = frcp(1.f + fexp2(acc[0]));
  float gf = frcp(1.f + fexp2(acc[1]));
  float gg = fmaf(2.f, frcp(1.f + fexp2(acc[2])), -1.f);
  float go = frcp(1.f + fexp2(acc[3]));
  c = fmaf(gf, c, gi * gg);
  float th = fmaf(2.f, frcp(1.f + fexp2(KTANH * c)), -1.f);
  float h = go * th;  // this lane's h_j(t)
#pragma unroll
  for (int u2 = 0; u2 < 5; ++u2) hAll[u2] = bperm(bp[u2], h);
}

// Role-split grid: blocks [0,nB) run lstm2a+2b (heavy, dispatched first);
// blocks [nB,2nB) run lstm1. 12 elements per 64-lane wave, 5 lanes each.
// h1 -> h1out (=d_out, FC overwrites later), h2b -> h2out (=d_ws).
__global__ __launch_bounds__(64, 2) void rnn_split_kernel(
    const float* __restrict__ x1, const float* __restrict__ x2,
    const float* __restrict__ Wih1, const float* __restrict__ Whh1,
    const float* __restrict__ bih1, const float* __restrict__ bhh1,
    const float* __restrict__ Wih2a, const float* __restrict__ Whh2a,
    const float* __restrict__ bih2a, const float* __restrict__ bhh2a,
    const float* __restrict__ Wih2b, const float* __restrict__ Whh2b,
    const float* __restrict__ bih2b, const float* __restrict__ bhh2b,
    float* __restrict__ h1out, float* __restrict__ h2out, int B, int nB) {
  const int l = threadIdx.x;
  const int g = l / 5;
  const int u = l - 5 * g;
  const bool act = (g < 12);
  const int el = act ? g : 11;
  const bool roleB = (blockIdx.x < (unsigned)nB);
  const int blk = roleB ? blockIdx.x : blockIdx.x - nB;
  const int eg = blk * 12 + el;
  const int egc = (eg < B) ? eg : (B - 1);

  int bp[5];
#pragma unroll
  for (int u2 = 0; u2 < 5; ++u2) bp[u2] = (5 * g + u2) * 4;

  if (roleB) {
    CellP Wa, Wb;
    load_cellP(Wa, u, Wih2a, Whh2a, bih2a, bhh2a);
    load_cellP(Wb, u, Wih2b, Whh2b, bih2b, bhh2b);
    const float* px = x2 + (size_t)egc * 640;

    float h2a[5], h2b[5];
    float c2 = 0.f, c3 = 0.f;
#pragma unroll
    for (int k = 0; k < 5; ++k) h2a[k] = h2b[k] = 0.f;
    f2 xp[2] = {(f2){px[0], px[1]}, (f2){px[2], px[3]}};
    float x4 = px[4];

    for (int t = 0; t < 128; ++t) {
      const int tn = (t < 127) ? t + 1 : 127;
      f2 n0 = (f2){px[tn * 5 + 0], px[tn * 5 + 1]};
      f2 n1 = (f2){px[tn * 5 + 2], px[tn * 5 + 3]};
      float n4 = px[tn * 5 + 4];
      stepP(Wa, xp, x4, h2a, c2, bp);
      f2 hp[2] = {(f2){h2a[0], h2a[1]}, (f2){h2a[2], h2a[3]}};
      stepP(Wb, hp, h2a[4], h2b, c3, bp);  // 2b consumes h2a(t)
      xp[0] = n0;
      xp[1] = n1;
      x4 = n4;
    }
    if (act && eg < B) h2out[(size_t)eg * 5 + u] = h2b[u];
  } else {
    CellP W0;
    load_cellP(W0, u, Wih1, Whh1, bih1, bhh1);
    const float* px = x1 + (size_t)egc * 640;

    float h1[5];
    float c1 = 0.f;
#pragma unroll
    for (int k = 0; k < 5; ++k) h1[k] = 0.f;
    f2 xp[2] = {(f2){px[0], px[1]}, (f2){px[2], px[3]}};
    float x4 = px[4];

    for (int t = 0; t < 128; ++t) {
      const int tn = (t < 127) ? t + 1 : 127;
      f2 n0 = (f2){px[tn * 5 + 0], px[tn * 5 + 1]};
      f2 n1 = (f2){px[tn * 5 + 2], px[tn * 5 + 3]};
      float n4 = px[tn * 5 + 4];
      stepP(W0, xp, x4, h1, c1, bp);
      xp[0] = n0;
      xp[1] = n1;
      x4 = n4;
    }
    if (act && eg < B) h1out[(size_t)eg * 5 + u] = h1[u];
  }
}

// One thread per element. wsh1 aliases out (read h1 before overwriting; both
// deliberately NOT __restrict). x-lasts read from global (L3-resident).
__global__ __launch_bounds__(64) void fc_kernel(
    const float* __restrict__ x1, const float* __restrict__ x2,
    const float* wsh1, const float* __restrict__ wsh2,
    const float* __restrict__ W1, const float* __restrict__ b1,
    const float* __restrict__ W2, const float* __restrict__ b2,
    const float* __restrict__ W3, const float* __restrict__ b3,
    const float* __restrict__ W4, const float* __restrict__ b4,
    const float* __restrict__ W5, const float* __restrict__ b5, float* out,
    int B) {
  int e = blockIdx.x * 64 + threadIdx.x;
  if (e >= B) return;
  float in0[20];
#pragma unroll
  for (int k = 0; k < 5; ++k) {
    in0[k] = x1[(size_t)e * 640 + 635 + k];
    in0[5 + k] = x2[(size_t)e * 640 + 635 + k];
    in0[10 + k] = wsh1[(size_t)e * 5 + k];
    in0[15 + k] = wsh2[(size_t)e * 5 + k];
  }
  float v1[32];
#pragma unroll
  for (int n = 0; n < 32; ++n) {
    float acc = b1[n];
#pragma unroll
    for (int k = 0; k < 20; ++k) acc = fmaf(W1[n * 20 + k], in0[k], acc);
    v1[n] = fmaxf(acc, 0.f);
  }
  float v2[32];
#pragma unroll
  for (int n = 0; n < 32; ++n) {
    float acc = b2[n];
#pragma unroll
    for (int k = 0; k < 32; ++k) acc = fmaf(W2[n * 32 + k], v1[k], acc);
    v2[n] = fmaxf(acc, 0.f);
  }
  float v3[16];
#pragma unroll
  for (int n = 0; n < 16; ++n) {
    float acc = b3[n];
#pragma unroll
    for (int k = 0; k < 32; ++k) acc = fmaf(W3[n * 32 + k], v2[k], acc);
    v3[n] = fmaxf(acc, 0.f);
  }
  float v4[16];
#pragma unroll
  for (int n = 0; n < 16; ++n) {
    float acc = b4[n];
#pragma unroll
    for (int k = 0; k < 16; ++k) acc = fmaf(W4[n * 16 + k], v3[k], acc);
    v4[n] = fmaxf(acc, 0.f);
  }
#pragma unroll
  for (int n = 0; n < 5; ++n) {
    float acc = b5[n];
#pragma unroll
    for (int k = 0; k < 16; ++k) acc = fmaf(W5[n * 16 + k], v4[k], acc);
    out[(size_t)e * 5 + n] = acc;
  }
}

extern "C" void kernel_launch(void* const* d_in, const int* in_sizes, int n_in,
                              void* d_out, int out_size, void* d_ws,
                              size_t ws_size, hipStream_t stream) {
  const float* x1 = (const float*)d_in[0];
  const float* x2 = (const float*)d_in[1];
  const float* Wih1 = (const float*)d_in[2];
  const float* Whh1 = (const float*)d_in[3];
  const float* bih1 = (const float*)d_in[4];
  const float* bhh1 = (const float*)d_in[5];
  const float* Wih2a = (const float*)d_in[6];
  const float* Whh2a = (const float*)d_in[7];
  const float* bih2a = (const float*)d_in[8];
  const float* bhh2a = (const float*)d_in[9];
  const float* Wih2b = (const float*)d_in[10];
  const float* Whh2b = (const float*)d_in[11];
  const float* bih2b = (const float*)d_in[12];
  const float* bhh2b = (const float*)d_in[13];
  const float* W1 = (const float*)d_in[14];
  const float* b1 = (const float*)d_in[15];
  const float* W2 = (const float*)d_in[16];
  const float* b2 = (const float*)d_in[17];
  const float* W3 = (const float*)d_in[18];
  const float* b3 = (const float*)d_in[19];
  const float* W4 = (const float*)d_in[20];
  const float* b4 = (const float*)d_in[21];
  const float* W5 = (const float*)d_in[22];
  const float* b5 = (const float*)d_in[23];

  int B = in_sizes[0] / 640;   // [B,128,5]
  int nB = (B + 11) / 12;      // blocks per role
  float* wsh1 = (float*)d_out; // h1 staged in d_out
  float* wsh2 = (float*)d_ws;  // h2b staged in ws (320 KB)

  rnn_split_kernel<<<2 * nB, 64, 0, stream>>>(
      x1, x2, Wih1, Whh1, bih1, bhh1, Wih2a, Whh2a, bih2a, bhh2a, Wih2b, Whh2b,
      bih2b, bhh2b, wsh1, wsh2, B, nB);
  fc_kernel<<<(B + 63) / 64, 64, 0, stream>>>(x1, x2, wsh1, wsh2, W1, b1, W2,
                                              b2, W3, b3, W4, b4, W5, b5,
                                              (float*)d_out, B);
}

// Round 6
// 224.271 us; speedup vs baseline: 1.1483x; 1.1483x over previous
//
#include <hip/hip_runtime.h>

#define DEV __device__ __forceinline__
#define KSIG (-1.442695041f)
#define KTANH (-2.885390082f)

typedef float f2 __attribute__((ext_vector_type(2)));

DEV float fexp2(float x) { return __builtin_amdgcn_exp2f(x); }
DEV float frcp(float x) { return __builtin_amdgcn_rcpf(x); }
DEV float bperm(int a, float x) {
  return __int_as_float(__builtin_amdgcn_ds_bpermute(a, __float_as_int(x)));
}
DEV f2 pkfma(f2 a, f2 b, f2 c) { return __builtin_elementwise_fma(a, b, c); }

// Lane u of a 5-lane group owns state index j=u and gate rows
// {u,5+u,10+u,15+u} (i,f,g,o). kexp folded into weights/bias: sigmoid rows
// scaled by KSIG, g-row by KTANH; act = rcp(1+exp2(acc)), tanh = 2*act-1.
struct CellP {
  f2 wx[4][2];
  f2 wh[4][2];
  float wx4[4], wh4[4];
  f2 b2[4];  // {bias, 0}
};

DEV void load_cellP(CellP& W, int u, const float* __restrict__ Wih,
                    const float* __restrict__ Whh,
                    const float* __restrict__ bih,
                    const float* __restrict__ bhh) {
#pragma unroll
  for (int rt = 0; rt < 4; ++rt) {  // 0=i 1=f 2=g 3=o
    int row = 5 * rt + u;
    float kx = (rt == 2) ? KTANH : KSIG;
    W.wx[rt][0] = (f2){kx * Wih[row * 5 + 0], kx * Wih[row * 5 + 1]};
    W.wx[rt][1] = (f2){kx * Wih[row * 5 + 2], kx * Wih[row * 5 + 3]};
    W.wx4[rt] = kx * Wih[row * 5 + 4];
    W.wh[rt][0] = (f2){kx * Whh[row * 5 + 0], kx * Whh[row * 5 + 1]};
    W.wh[rt][1] = (f2){kx * Whh[row * 5 + 2], kx * Whh[row * 5 + 3]};
    W.wh4[rt] = kx * Whh[row * 5 + 4];
    W.b2[rt] = (f2){kx * (bih[row] + bhh[row]), 0.f};
  }
}

// One cell timestep; returns this lane's own h_j(t). hAll: h(t-1) in, h(t) out.
DEV float stepP(const CellP& W, const f2 xp[2], float x4, float hAll[5],
                float& c, const int bp[5]) {
  f2 hp0 = (f2){hAll[0], hAll[1]};
  f2 hp1 = (f2){hAll[2], hAll[3]};
  float acc[4];
#pragma unroll
  for (int rt = 0; rt < 4; ++rt) {
    f2 a2 = pkfma(W.wx[rt][0], xp[0], W.b2[rt]);
    a2 = pkfma(W.wx[rt][1], xp[1], a2);
    a2 = pkfma(W.wh[rt][0], hp0, a2);
    a2 = pkfma(W.wh[rt][1], hp1, a2);
    float a = a2.x + a2.y;
    a = fmaf(W.wx4[rt], x4, a);
    acc[rt] = fmaf(W.wh4[rt], hAll[4], a);
  }
  float gi = frcp(1.f + fexp2(acc[0]));
  float gf = frcp(1.f + fexp2(acc[1]));
  float gg = fmaf(2.f, frcp(1.f + fexp2(acc[2])), -1.f);
  float go = frcp(1.f + fexp2(acc[3]));
  c = fmaf(gf, c, gi * gg);
  float th = fmaf(2.f, frcp(1.f + fexp2(KTANH * c)), -1.f);
  float h = go * th;
#pragma unroll
  for (int u2 = 0; u2 < 5; ++u2) hAll[u2] = bperm(bp[u2], h);
  return h;
}

// Block = 192 threads = 3 waves, 12 elements (5 lanes each; lanes 60..63 idle).
// wave0: lstm1. wave1: lstm2a, publishes h2a(t) to sH[t&1]. wave2: lstm2b,
// one step behind, consumes sH[(t-1)&1]. One __syncthreads per timestep.
// FC stack fused at the end, task-split over all 192 lanes.
__global__ __launch_bounds__(192, 4) void rnn3w_kernel(
    const float* __restrict__ x1, const float* __restrict__ x2,
    const float* __restrict__ Wih1, const float* __restrict__ Whh1,
    const float* __restrict__ bih1, const float* __restrict__ bhh1,
    const float* __restrict__ Wih2a, const float* __restrict__ Whh2a,
    const float* __restrict__ bih2a, const float* __restrict__ bhh2a,
    const float* __restrict__ Wih2b, const float* __restrict__ Whh2b,
    const float* __restrict__ bih2b, const float* __restrict__ bhh2b,
    const float* __restrict__ W1, const float* __restrict__ b1,
    const float* __restrict__ W2, const float* __restrict__ b2,
    const float* __restrict__ W3, const float* __restrict__ b3,
    const float* __restrict__ W4, const float* __restrict__ b4,
    const float* __restrict__ W5, const float* __restrict__ b5,
    float* __restrict__ out, int B) {
  __shared__ float sH[2][64];  // h2a handoff ring: [buf][g*5+u]
  __shared__ float sIn[12][20];
  __shared__ float sA[12][32];
  __shared__ float sB[12][32];

  const int tid = threadIdx.x;
  const int w = tid >> 6;  // wave role: 0=lstm1 1=lstm2a 2=lstm2b
  const int l = tid & 63;
  const int g = l / 5;
  const int u = l - 5 * g;
  const bool act = (g < 12);
  const int el = act ? g : 11;
  const int eg = blockIdx.x * 12 + el;
  const int egc = (eg < B) ? eg : (B - 1);

  CellP W;
  if (w == 0)
    load_cellP(W, u, Wih1, Whh1, bih1, bhh1);
  else if (w == 1)
    load_cellP(W, u, Wih2a, Whh2a, bih2a, bhh2a);
  else
    load_cellP(W, u, Wih2b, Whh2b, bih2b, bhh2b);

  int bp[5];
#pragma unroll
  for (int u2 = 0; u2 < 5; ++u2) bp[u2] = (5 * g + u2) * 4;

  const float* px = ((w == 0) ? x1 : x2) + (size_t)egc * 640;

  if (tid < 128) sH[tid >> 6][tid & 63] = 0.f;

  float hAll[5];
  float c = 0.f, hOwn = 0.f;
#pragma unroll
  for (int k = 0; k < 5; ++k) hAll[k] = 0.f;

  f2 xp[2];
  float x4 = 0.f;
  if (w < 2) {
    xp[0] = (f2){px[0], px[1]};
    xp[1] = (f2){px[2], px[3]};
    x4 = px[4];
  }
  __syncthreads();  // sH zeroed before wave2's first (junk) read

  for (int t = 0; t < 128; ++t) {
    f2 xin[2];
    float xin4;
    if (w == 2) {  // h2a(t-1); t=0 reads zeroed buf (junk step, discarded)
      const float* s = &sH[(t + 1) & 1][g * 5];
      xin[0] = (f2){s[0], s[1]};
      xin[1] = (f2){s[2], s[3]};
      xin4 = s[4];
    } else {
      xin[0] = xp[0];
      xin[1] = xp[1];
      xin4 = x4;
    }
    if (w < 2) {  // prefetch x(t+1)
      const int tn = (t < 127) ? t + 1 : 127;
      xp[0] = (f2){px[tn * 5 + 0], px[tn * 5 + 1]};
      xp[1] = (f2){px[tn * 5 + 2], px[tn * 5 + 3]};
      x4 = px[tn * 5 + 4];
    }
    hOwn = stepP(W, xin, xin4, hAll, c, bp);
    if (w == 2 && t == 0) {  // discard the junk step; h2b/c restart from 0
#pragma unroll
      for (int k = 0; k < 5; ++k) hAll[k] = 0.f;
      c = 0.f;
      hOwn = 0.f;
    }
    if (w == 1 && act) sH[t & 1][g * 5 + u] = hOwn;  // publish h2a(t)
    __syncthreads();
  }

  // wave2 trails by one: consume h2a(127) from sH[127&1]=sH[1]
  if (w == 2) {
    const float* s = &sH[1][g * 5];
    f2 xin[2] = {(f2){s[0], s[1]}, (f2){s[2], s[3]}};
    hOwn = stepP(W, xin, s[4], hAll, c, bp);
  }

  // Stage FC inputs: [x1_last, x2_last, h1, h2b]
  if (act) {
    if (w == 0) {
      sIn[el][u] = x1[(size_t)egc * 640 + 635 + u];
      sIn[el][10 + u] = hOwn;  // h1(127), own j=u
    } else if (w == 1) {
      sIn[el][5 + u] = x2[(size_t)egc * 640 + 635 + u];
    } else {
      sIn[el][15 + u] = hOwn;  // h2b(127)
    }
  }
  __syncthreads();

  // FC stack: task-split over 192 lanes; weights from global (L1-cached).
  for (int task = tid; task < 12 * 32; task += 192) {
    int e = task >> 5, n = task & 31;
    float acc = b1[n];
#pragma unroll
    for (int k = 0; k < 20; ++k) acc = fmaf(W1[n * 20 + k], sIn[e][k], acc);
    sA[e][n] = fmaxf(acc, 0.f);
  }
  __syncthreads();
  for (int task = tid; task < 12 * 32; task += 192) {
    int e = task >> 5, n = task & 31;
    float acc = b2[n];
#pragma unroll
    for (int k = 0; k < 32; ++k) acc = fmaf(W2[n * 32 + k], sA[e][k], acc);
    sB[e][n] = fmaxf(acc, 0.f);
  }
  __syncthreads();
  {  // 12*16 = 192 tasks, exactly one per lane
    int e = tid >> 4, n = tid & 15;
    float acc = b3[n];
#pragma unroll
    for (int k = 0; k < 32; ++k) acc = fmaf(W3[n * 32 + k], sB[e][k], acc);
    sA[e][n] = fmaxf(acc, 0.f);  // reuse sA cols 0..15
  }
  __syncthreads();
  {
    int e = tid >> 4, n = tid & 15;
    float acc = b4[n];
#pragma unroll
    for (int k = 0; k < 16; ++k) acc = fmaf(W4[n * 16 + k], sA[e][k], acc);
    sB[e][n] = fmaxf(acc, 0.f);
  }
  __syncthreads();
  if (tid < 60) {  // 12 elems x 5 outputs
    int e = tid / 5, n = tid - 5 * (tid / 5);
    float acc = b5[n];
#pragma unroll
    for (int k = 0; k < 16; ++k) acc = fmaf(W5[n * 16 + k], sB[e][k], acc);
    int ego = blockIdx.x * 12 + e;
    if (ego < B) out[(size_t)ego * 5 + n] = acc;
  }
}

extern "C" void kernel_launch(void* const* d_in, const int* in_sizes, int n_in,
                              void* d_out, int out_size, void* d_ws,
                              size_t ws_size, hipStream_t stream) {
  const float* x1 = (const float*)d_in[0];
  const float* x2 = (const float*)d_in[1];
  const float* Wih1 = (const float*)d_in[2];
  const float* Whh1 = (const float*)d_in[3];
  const float* bih1 = (const float*)d_in[4];
  const float* bhh1 = (const float*)d_in[5];
  const float* Wih2a = (const float*)d_in[6];
  const float* Whh2a = (const float*)d_in[7];
  const float* bih2a = (const float*)d_in[8];
  const float* bhh2a = (const float*)d_in[9];
  const float* Wih2b = (const float*)d_in[10];
  const float* Whh2b = (const float*)d_in[11];
  const float* bih2b = (const float*)d_in[12];
  const float* bhh2b = (const float*)d_in[13];
  const float* W1 = (const float*)d_in[14];
  const float* b1 = (const float*)d_in[15];
  const float* W2 = (const float*)d_in[16];
  const float* b2 = (const float*)d_in[17];
  const float* W3 = (const float*)d_in[18];
  const float* b3 = (const float*)d_in[19];
  const float* W4 = (const float*)d_in[20];
  const float* b4 = (const float*)d_in[21];
  const float* W5 = (const float*)d_in[22];
  const float* b5 = (const float*)d_in[23];

  int B = in_sizes[0] / 640;  // [B,128,5]
  int nB = (B + 11) / 12;     // 12 elements per block

  rnn3w_kernel<<<nB, 192, 0, stream>>>(
      x1, x2, Wih1, Whh1, bih1, bhh1, Wih2a, Whh2a, bih2a, bhh2a, Wih2b, Whh2b,
      bih2b, bhh2b, W1, b1, W2, b2, W3, b3, W4, b4, W5, b5, (float*)d_out, B);
}